// Round 1
// 91.382 us; speedup vs baseline: 1.0367x; 1.0367x over previous
//
#include <hip/hip_runtime.h>
#include <math.h>

#define NUM_GRAPHS 16
#define PI_F 3.14159265358979323846f
#define INV_SQRT_2PI 0.3989422804014327f

// Kernel A: out[g] = -0.5 * (sum_g q^2) / sqrt(2*pi)
// batch is sorted -> chunk-per-thread run-length accumulation, ~1-2 LDS
// atomics per thread instead of one per node (old version serialized
// 64-way on the shared accumulator because all lanes hit the same graph).
__global__ void gto_init_kernel(const float* __restrict__ q,
                                const int* __restrict__ batch, int n_nodes,
                                float* __restrict__ out) {
    __shared__ float acc[NUM_GRAPHS];
    int t = threadIdx.x;
    if (t < NUM_GRAPHS) acc[t] = 0.f;
    __syncthreads();

    int chunk = (n_nodes + blockDim.x - 1) / (int)blockDim.x;
    int i0 = t * chunk;
    int i1 = min(n_nodes, i0 + chunk);
    int cur = -1;
    float sum = 0.f;
    for (int i = i0; i < i1; ++i) {
        int b = batch[i];
        float qi = q[i];
        if (b != cur) {
            if (cur >= 0) atomicAdd(&acc[cur], sum);
            cur = b;
            sum = 0.f;
        }
        sum = fmaf(qi, qi, sum);
    }
    if (cur >= 0) atomicAdd(&acc[cur], sum);
    __syncthreads();
    if (t < NUM_GRAPHS) out[t] = -0.5f * acc[t] * INV_SQRT_2PI;
}

#define WAVES_PER_BLOCK 4
#define K_PER_WAVE 8
#define K_PER_BLOCK (WAVES_PER_BLOCK * K_PER_WAVE)

// Kernel B: per-k structure factors + energy accumulation.
// Segment boundaries are computed per-block (17 binary searches over the
// sorted batch array) so NO workspace is needed at all — the previous
// version parked node_start in d_ws, which (theory) dragged a 256 MiB
// workspace poison-fill into the timed path.
__global__ void __launch_bounds__(256)
gto_energy_kernel(const float* __restrict__ kvec,   // [K,3]
                  const float* __restrict__ knorm2, // [K]
                  const int*   __restrict__ kbatch, // [K] sorted
                  const float* __restrict__ k0mask, // [K]
                  const float* __restrict__ q,      // [N]
                  const float* __restrict__ pos,    // [N,3]
                  const float* __restrict__ volume, // [B]
                  const int*   __restrict__ batch,  // [N] sorted
                  float* __restrict__ out, int K, int N) {
    __shared__ float gacc[NUM_GRAPHS];
    __shared__ int sstart[NUM_GRAPHS + 1];
    int t = threadIdx.x;
    if (t < NUM_GRAPHS) gacc[t] = 0.f;
    // lower_bound(batch, g) for g = 0..NUM_GRAPHS, one thread each
    if (t <= NUM_GRAPHS) {
        int lo = 0, hi = N;
        while (lo < hi) {
            int mid = (lo + hi) >> 1;
            if (batch[mid] < t) lo = mid + 1; else hi = mid;
        }
        sstart[t] = lo;
    }
    __syncthreads();

    int wave = t >> 6;
    int lane = t & 63;
    int kbase = (blockIdx.x * WAVES_PER_BLOCK + wave) * K_PER_WAVE;

    for (int kk = 0; kk < K_PER_WAVE; ++kk) {
        int k = kbase + kk;
        if (k >= K) break;
        int g = kbatch[k];
        float kx = kvec[3 * k + 0];
        float ky = kvec[3 * k + 1];
        float kz = kvec[3 * k + 2];
        int s = sstart[g];
        int e = sstart[g + 1];

        float C = 0.f, S = 0.f;
        for (int j = s + lane; j < e; j += 64) {
            float px = pos[3 * j + 0];
            float py = pos[3 * j + 1];
            float pz = pos[3 * j + 2];
            float inner = fmaf(kx, px, fmaf(ky, py, kz * pz));
            float sv, cv;
            __sincosf(inner, &sv, &cv);
            float qj = q[j];
            C = fmaf(cv, qj, C);
            S = fmaf(sv, qj, S);
        }
        // 64-lane butterfly reduce
        #pragma unroll
        for (int off = 32; off > 0; off >>= 1) {
            C += __shfl_xor(C, off, 64);
            S += __shfl_xor(S, off, 64);
        }
        if (lane == 0) {
            float kn2 = knorm2[k];
            float fs2 = __expf(-kn2);                 // fs^2, sigma = 1
            float kfac = (k0mask[k] > 0.f) ? 0.f : 1.f / kn2;
            float e_k = 4.f * PI_F * kfac * fs2 * (C * C + S * S) / volume[g];
            atomicAdd(&gacc[g], e_k);
        }
    }
    __syncthreads();
    if (t < NUM_GRAPHS && gacc[t] != 0.f) {
        atomicAdd(&out[t], gacc[t]);
    }
}

extern "C" void kernel_launch(void* const* d_in, const int* in_sizes, int n_in,
                              void* d_out, int out_size, void* d_ws, size_t ws_size,
                              hipStream_t stream) {
    const float* k_vectors  = (const float*)d_in[0];  // [K,3]
    const float* k_norm2    = (const float*)d_in[1];  // [K]
    const int*   k_batch    = (const int*)  d_in[2];  // [K]
    const float* k0_mask    = (const float*)d_in[3];  // [K]
    const float* src_feats  = (const float*)d_in[4];  // [N,1]
    const float* positions  = (const float*)d_in[5];  // [N,3]
    const int*   batch      = (const int*)  d_in[6];  // [N]
    const float* volume     = (const float*)d_in[7];  // [B]
    // d_in[8] = pbc (bool [B,3]) — unused by the math
    // d_ws: intentionally UNUSED (theory: ws use pulls a 256 MiB poison
    // fill into the timed path)

    int K = in_sizes[1];
    int N = in_sizes[4];
    float* out = (float*)d_out;

    gto_init_kernel<<<1, 256, 0, stream>>>(src_feats, batch, N, out);

    int blocks = (K + K_PER_BLOCK - 1) / K_PER_BLOCK;
    gto_energy_kernel<<<blocks, 256, 0, stream>>>(
        k_vectors, k_norm2, k_batch, k0_mask, src_feats, positions,
        volume, batch, out, K, N);
}

// Round 2
// 85.394 us; speedup vs baseline: 1.1094x; 1.0701x over previous
//
#include <hip/hip_runtime.h>
#include <math.h>

#define NUM_GRAPHS 16
#define PI_F 3.14159265358979323846f
#define INV_SQRT_2PI 0.3989422804014327f

#define WAVES_PER_BLOCK 4
#define K_PER_WAVE 8
#define K_PER_BLOCK (WAVES_PER_BLOCK * K_PER_WAVE)

// Single fused kernel. out[] must be zeroed beforehand (hipMemsetAsync).
// Blocks 0..NUM_GRAPHS-1: self-energy for graph g (atomicAdd -0.5*sum(q^2)/sqrt(2pi)).
// Blocks NUM_GRAPHS.. : k-space energy, 32 k-values per block, 8 per wave.
__global__ void __launch_bounds__(256)
gto_fused_kernel(const float* __restrict__ kvec,   // [K,3]
                 const float* __restrict__ knorm2, // [K]
                 const int*   __restrict__ kbatch, // [K] sorted
                 const float* __restrict__ k0mask, // [K]
                 const float* __restrict__ q,      // [N]
                 const float* __restrict__ pos,    // [N,3]
                 const float* __restrict__ volume, // [B]
                 const int*   __restrict__ batch,  // [N] sorted
                 float* __restrict__ out, int K, int N) {
    __shared__ float gacc[NUM_GRAPHS];
    __shared__ int   sstart[NUM_GRAPHS + 1];
    __shared__ float wsum[WAVES_PER_BLOCK];

    int bid  = blockIdx.x;
    int t    = threadIdx.x;
    int wave = t >> 6;
    int lane = t & 63;

    if (bid < NUM_GRAPHS) {
        // ---- self-energy block: one graph per block, runs concurrently
        // with the k-blocks (no kernel-level serialization anymore) ----
        int g = bid;
        // bounds: wave-uniform binary searches (values identical across threads)
        int lo = 0, hi = N;
        while (lo < hi) { int mid = (lo + hi) >> 1; if (batch[mid] < g)     lo = mid + 1; else hi = mid; }
        int s = lo;
        lo = 0; hi = N;
        while (lo < hi) { int mid = (lo + hi) >> 1; if (batch[mid] < g + 1) lo = mid + 1; else hi = mid; }
        int e = lo;

        float sum = 0.f;
        for (int i = s + t; i < e; i += 256) { float qi = q[i]; sum = fmaf(qi, qi, sum); }
        #pragma unroll
        for (int off = 32; off > 0; off >>= 1) sum += __shfl_xor(sum, off, 64);
        if (lane == 0) wsum[wave] = sum;
        __syncthreads();
        if (t == 0) {
            float s4 = wsum[0] + wsum[1] + wsum[2] + wsum[3];
            atomicAdd(&out[g], -0.5f * s4 * INV_SQRT_2PI);
        }
        return;
    }

    // ---- k-space blocks ----
    if (t < NUM_GRAPHS) gacc[t] = 0.f;

    int kbase = ((bid - NUM_GRAPHS) * WAVES_PER_BLOCK + wave) * K_PER_WAVE;

    // Prefetch this wave's 8 k-records BEFORE the barrier so the issue of
    // these (wave-uniform) loads overlaps the dependent-load binary-search
    // chain below instead of serializing after it.
    float kx[K_PER_WAVE], ky[K_PER_WAVE], kz[K_PER_WAVE];
    float kn2[K_PER_WAVE], kmk[K_PER_WAVE];
    int   kg[K_PER_WAVE];
    #pragma unroll
    for (int kk = 0; kk < K_PER_WAVE; ++kk) {
        int k = kbase + kk; if (k > K - 1) k = K - 1;
        kx[kk]  = kvec[3 * k + 0];
        ky[kk]  = kvec[3 * k + 1];
        kz[kk]  = kvec[3 * k + 2];
        kn2[kk] = knorm2[k];
        kmk[kk] = k0mask[k];
        kg[kk]  = kbatch[k];
    }

    // segment boundaries: lower_bound(batch, g), 17 parallel searches
    if (t <= NUM_GRAPHS) {
        int lo = 0, hi = N;
        while (lo < hi) { int mid = (lo + hi) >> 1; if (batch[mid] < t) lo = mid + 1; else hi = mid; }
        sstart[t] = lo;
    }
    __syncthreads();

    #pragma unroll
    for (int kk = 0; kk < K_PER_WAVE; ++kk) {
        int k = kbase + kk;
        if (k >= K) break;
        int g = kg[kk];
        int s = sstart[g];
        int e = sstart[g + 1];

        float C = 0.f, S = 0.f;
        for (int j = s + lane; j < e; j += 64) {
            float px = pos[3 * j + 0];
            float py = pos[3 * j + 1];
            float pz = pos[3 * j + 2];
            float inner = fmaf(kx[kk], px, fmaf(ky[kk], py, kz[kk] * pz));
            float sv, cv;
            __sincosf(inner, &sv, &cv);
            float qj = q[j];
            C = fmaf(cv, qj, C);
            S = fmaf(sv, qj, S);
        }
        #pragma unroll
        for (int off = 32; off > 0; off >>= 1) {
            C += __shfl_xor(C, off, 64);
            S += __shfl_xor(S, off, 64);
        }
        if (lane == 0) {
            float fs2  = __expf(-kn2[kk]);               // fs^2, sigma = 1
            float kfac = (kmk[kk] > 0.f) ? 0.f : 1.f / kn2[kk];
            float e_k  = 4.f * PI_F * kfac * fs2 * (C * C + S * S) / volume[g];
            atomicAdd(&gacc[g], e_k);
        }
    }
    __syncthreads();
    if (t < NUM_GRAPHS && gacc[t] != 0.f) {
        atomicAdd(&out[t], gacc[t]);
    }
}

extern "C" void kernel_launch(void* const* d_in, const int* in_sizes, int n_in,
                              void* d_out, int out_size, void* d_ws, size_t ws_size,
                              hipStream_t stream) {
    const float* k_vectors  = (const float*)d_in[0];  // [K,3]
    const float* k_norm2    = (const float*)d_in[1];  // [K]
    const int*   k_batch    = (const int*)  d_in[2];  // [K]
    const float* k0_mask    = (const float*)d_in[3];  // [K]
    const float* src_feats  = (const float*)d_in[4];  // [N,1]
    const float* positions  = (const float*)d_in[5];  // [N,3]
    const int*   batch      = (const int*)  d_in[6];  // [N]
    const float* volume     = (const float*)d_in[7];  // [B]
    // d_in[8] = pbc (bool [B,3]) — unused by the math
    // d_ws unused; the harness's 256 MiB workspace poison fills are
    // unconditional (verified R0->R1: removing ws use did not remove them).

    int K = in_sizes[1];
    int N = in_sizes[4];
    float* out = (float*)d_out;

    hipMemsetAsync(out, 0, out_size, stream);

    int kblocks = (K + K_PER_BLOCK - 1) / K_PER_BLOCK;
    gto_fused_kernel<<<kblocks + NUM_GRAPHS, 256, 0, stream>>>(
        k_vectors, k_norm2, k_batch, k0_mask, src_feats, positions,
        volume, batch, out, K, N);
}

// Round 3
// 84.098 us; speedup vs baseline: 1.1265x; 1.0154x over previous
//
#include <hip/hip_runtime.h>
#include <math.h>

#define NUM_GRAPHS 16
#define PI_F 3.14159265358979323846f
#define INV_SQRT_2PI 0.3989422804014327f

#define WAVES_PER_BLOCK 4
#define K_PER_WAVE 8
#define K_PER_BLOCK (WAVES_PER_BLOCK * K_PER_WAVE)
#define SCAN_CHUNK 16

// Single fused kernel. out[] zeroed by hipMemsetAsync beforehand.
// Blocks 0..NUM_GRAPHS-1: self-energy for graph g.
// Blocks NUM_GRAPHS.. : k-space energy, 32 k-values/block, 8/wave.
// Segment boundaries via parallel transition scan (independent coalesced
// int4 loads) instead of binary search (12 DEPENDENT L2 loads ~0.9us that
// sat on every block's critical path; self blocks paid it twice).
__global__ void __launch_bounds__(256)
gto_fused_kernel(const float* __restrict__ kvec,   // [K,3]
                 const float* __restrict__ knorm2, // [K]
                 const int*   __restrict__ kbatch, // [K] sorted
                 const float* __restrict__ k0mask, // [K]
                 const float* __restrict__ q,      // [N]
                 const float* __restrict__ pos,    // [N,3]
                 const float* __restrict__ volume, // [B]
                 const int*   __restrict__ batch,  // [N] sorted
                 float* __restrict__ out, int K, int N) {
    __shared__ float gacc[NUM_GRAPHS];
    __shared__ int   sstart[NUM_GRAPHS + 1];
    __shared__ float wsum[WAVES_PER_BLOCK];

    int bid  = blockIdx.x;
    int t    = threadIdx.x;
    int wave = t >> 6;
    int lane = t & 63;
    bool is_self = (bid < NUM_GRAPHS);

    if (t < NUM_GRAPHS) gacc[t] = 0.f;

    // k-record prefetch (wave-uniform), issued BEFORE the scan so these
    // loads are in flight while the scan runs.
    float kx[K_PER_WAVE], ky[K_PER_WAVE], kz[K_PER_WAVE];
    float kn2[K_PER_WAVE], kmk[K_PER_WAVE];
    int   kg[K_PER_WAVE];
    int   kbase = 0;
    if (!is_self) {
        kbase = ((bid - NUM_GRAPHS) * WAVES_PER_BLOCK + wave) * K_PER_WAVE;
        #pragma unroll
        for (int kk = 0; kk < K_PER_WAVE; ++kk) {
            int k = kbase + kk; if (k > K - 1) k = K - 1;
            kx[kk]  = kvec[3 * k + 0];
            ky[kk]  = kvec[3 * k + 1];
            kz[kk]  = kvec[3 * k + 2];
            kn2[kk] = knorm2[k];
            kmk[kk] = k0mask[k];
            kg[kk]  = kbatch[k];
        }
    }

    // ---- segment-boundary transition scan ----
    // Each thread scans SCAN_CHUNK consecutive batch entries (int4 loads,
    // all independent); at each value transition a..b it owns, it writes
    // sstart[g]=i for g in (a..b]. Thread at position 0 seeds prev=-1 so
    // sstart[0..batch[0]] = 0; the thread owning N-1 fills the tail to N.
    for (int base = t * SCAN_CHUNK; base < N; base += blockDim.x * SCAN_CHUNK) {
        int prev = (base == 0) ? -1 : batch[base - 1];
        int lim = N - base; if (lim > SCAN_CHUNK) lim = SCAN_CHUNK;
        if (lim == SCAN_CHUNK && ((base & 3) == 0)) {
            const int4* p = (const int4*)(batch + base);
            int vals[SCAN_CHUNK];
            #pragma unroll
            for (int u = 0; u < SCAN_CHUNK / 4; ++u) {
                int4 v = p[u];
                vals[4*u+0] = v.x; vals[4*u+1] = v.y;
                vals[4*u+2] = v.z; vals[4*u+3] = v.w;
            }
            #pragma unroll
            for (int u = 0; u < SCAN_CHUNK; ++u) {
                int b = vals[u];
                if (b != prev) {
                    for (int g = prev + 1; g <= b; ++g) sstart[g] = base + u;
                    prev = b;
                }
            }
        } else {
            for (int u = 0; u < lim; ++u) {
                int b = batch[base + u];
                if (b != prev) {
                    for (int g = prev + 1; g <= b; ++g) sstart[g] = base + u;
                    prev = b;
                }
            }
        }
        if (base + lim == N) {
            for (int g = prev + 1; g <= NUM_GRAPHS; ++g) sstart[g] = N;
        }
    }
    __syncthreads();

    if (is_self) {
        // ---- self-energy block: one graph per block ----
        int g = bid;
        int s = sstart[g], e = sstart[g + 1];
        float sum = 0.f;
        for (int i = s + t; i < e; i += 256) { float qi = q[i]; sum = fmaf(qi, qi, sum); }
        #pragma unroll
        for (int off = 32; off > 0; off >>= 1) sum += __shfl_xor(sum, off, 64);
        if (lane == 0) wsum[wave] = sum;
        __syncthreads();
        if (t == 0) {
            float s4 = wsum[0] + wsum[1] + wsum[2] + wsum[3];
            atomicAdd(&out[g], -0.5f * s4 * INV_SQRT_2PI);
        }
        return;
    }

    // ---- k-space blocks ----
    #pragma unroll
    for (int kk = 0; kk < K_PER_WAVE; ++kk) {
        int k = kbase + kk;
        if (k >= K) break;
        int g = kg[kk];
        int s = sstart[g];
        int e = sstart[g + 1];

        float C = 0.f, S = 0.f;
        for (int j = s + lane; j < e; j += 64) {
            float px = pos[3 * j + 0];
            float py = pos[3 * j + 1];
            float pz = pos[3 * j + 2];
            float inner = fmaf(kx[kk], px, fmaf(ky[kk], py, kz[kk] * pz));
            float sv, cv;
            __sincosf(inner, &sv, &cv);
            float qj = q[j];
            C = fmaf(cv, qj, C);
            S = fmaf(sv, qj, S);
        }
        #pragma unroll
        for (int off = 32; off > 0; off >>= 1) {
            C += __shfl_xor(C, off, 64);
            S += __shfl_xor(S, off, 64);
        }
        if (lane == 0) {
            float fs2  = __expf(-kn2[kk]);               // fs^2, sigma = 1
            float kfac = (kmk[kk] > 0.f) ? 0.f : 1.f / kn2[kk];
            float e_k  = 4.f * PI_F * kfac * fs2 * (C * C + S * S) / volume[g];
            atomicAdd(&gacc[g], e_k);
        }
    }
    __syncthreads();
    if (t < NUM_GRAPHS && gacc[t] != 0.f) {
        atomicAdd(&out[t], gacc[t]);
    }
}

extern "C" void kernel_launch(void* const* d_in, const int* in_sizes, int n_in,
                              void* d_out, int out_size, void* d_ws, size_t ws_size,
                              hipStream_t stream) {
    const float* k_vectors  = (const float*)d_in[0];  // [K,3]
    const float* k_norm2    = (const float*)d_in[1];  // [K]
    const int*   k_batch    = (const int*)  d_in[2];  // [K]
    const float* k0_mask    = (const float*)d_in[3];  // [K]
    const float* src_feats  = (const float*)d_in[4];  // [N,1]
    const float* positions  = (const float*)d_in[5];  // [N,3]
    const int*   batch      = (const int*)  d_in[6];  // [N]
    const float* volume     = (const float*)d_in[7];  // [B]
    // d_in[8] = pbc — unused. d_ws unused (256 MiB poison fills are
    // unconditional harness behavior, verified R0->R1).

    int K = in_sizes[1];
    int N = in_sizes[4];
    float* out = (float*)d_out;

    hipMemsetAsync(out, 0, out_size, stream);

    int kblocks = (K + K_PER_BLOCK - 1) / K_PER_BLOCK;
    gto_fused_kernel<<<kblocks + NUM_GRAPHS, 256, 0, stream>>>(
        k_vectors, k_norm2, k_batch, k0_mask, src_feats, positions,
        volume, batch, out, K, N);
}